// Round 1
// baseline (1387.248 us; speedup 1.0000x reference)
//
#include <hip/hip_runtime.h>
#include <hip/hip_bf16.h>

#define BB 2
#define TT 2048
#define CCH 1024
#define NH 16
#define HD 64

// ---------------------------------------------------------------------------
// 16B-granular XOR swizzle for 64x64 fp32 LDS tiles (row stride 64 floats).
// Element block (r, d0/4) stored at column-block (d0/4) ^ ((r>>2)&7).
// Makes row-indexed b128 reads (16 lanes reading rows tx*4+cc at the same d0)
// spread over all 8 bank groups instead of landing on one.
__device__ __forceinline__ int swz_off(int r, int d0) {
    return (r << 6) + ((((d0 >> 2) ^ ((r >> 2) & 7)) << 2));
}

// ---------------------------------------------------------------------------
// Y = X @ W + bias.  X:[M=4096,1024] W:[1024,1024] bias:[1024]
// HEAD_LAYOUT: Y[((b*NH+n)*TT + t)*HD + d]   (b = row>>11, t = row&2047,
//              n = col>>6, d = col&63)       else Y[row*1024 + col].
// 64x64 tile, BK=16, 256 threads, 4x4 per thread.
template<bool HEAD_LAYOUT>
__global__ __launch_bounds__(256, 4)
void proj_gemm(const float* __restrict__ X, const float* __restrict__ W,
               const float* __restrict__ bias, float* __restrict__ Y)
{
    __shared__ __align__(16) float As[16][68];   // [kk][row], padded: conflict-free transpose stores
    __shared__ __align__(16) float Bs[16][64];   // [kk][col]
    const int t  = threadIdx.x;
    const int tx = t & 15, ty = t >> 4;
    const int row0 = blockIdx.x * 64;
    const int col0 = blockIdx.y * 64;

    const int arow = t >> 2, kc = (t & 3) << 2;   // A tile loader mapping
    const int brow = ty,     bc = tx << 2;        // B tile loader mapping

    float acc[4][4] = {};

    for (int k0 = 0; k0 < CCH; k0 += 16) {
        // issue global loads before the barrier so latency overlaps prior compute
        const float4 a4 = *(const float4*)&X[(long)(row0 + arow) * CCH + k0 + kc];
        const float4 b4 = *(const float4*)&W[(long)(k0 + brow) * CCH + col0 + bc];
        __syncthreads();                       // protect previous iteration's reads
        As[kc + 0][arow] = a4.x; As[kc + 1][arow] = a4.y;
        As[kc + 2][arow] = a4.z; As[kc + 3][arow] = a4.w;
        *(float4*)&Bs[brow][bc] = b4;
        __syncthreads();
        #pragma unroll
        for (int kk = 0; kk < 16; ++kk) {
            const float4 a = *(const float4*)&As[kk][ty << 2];
            const float4 b = *(const float4*)&Bs[kk][tx << 2];
            const float av[4] = {a.x, a.y, a.z, a.w};
            const float bv[4] = {b.x, b.y, b.z, b.w};
            #pragma unroll
            for (int i = 0; i < 4; ++i)
                #pragma unroll
                for (int j = 0; j < 4; ++j)
                    acc[i][j] += av[i] * bv[j];
        }
    }

    const int col = col0 + (tx << 2);
    const float4 bias4 = *(const float4*)&bias[col];
    #pragma unroll
    for (int rr = 0; rr < 4; ++rr) {
        const int row = row0 + (ty << 2) + rr;
        float4 o;
        o.x = acc[rr][0] + bias4.x; o.y = acc[rr][1] + bias4.y;
        o.z = acc[rr][2] + bias4.z; o.w = acc[rr][3] + bias4.w;
        if (HEAD_LAYOUT) {
            const int b = row >> 11, tt = row & (TT - 1);
            const int n = col >> 6, d = col & 63;
            *(float4*)&Y[((long)((b * NH + n) * TT + tt)) * HD + d] = o;
        } else {
            *(float4*)&Y[(long)row * CCH + col] = o;
        }
    }
}

// ---------------------------------------------------------------------------
// Flash attention with swapped roles:
//   score[i,j] = (Qeff[i] . Keff[j]) / 8,  Qeff = k-proj, Keff = q-proj,
//   causal j <= i, softmax over j, out[i] = sum_j p[i,j] V[j].
// One WG per (bn, 64-row q-tile). 256 threads, 4x4 register blocking.
__global__ __launch_bounds__(256, 2)
void attn_fused(const float* __restrict__ Qp, const float* __restrict__ Kp,
                const float* __restrict__ Vp, float* __restrict__ Yb)
{
    __shared__ __align__(16) float Qs[64 * 64];
    __shared__ __align__(16) float Ks[64 * 64];
    __shared__ __align__(16) float Vs[64 * 64];
    __shared__ __align__(16) float Ps[64 * 64];

    const int t  = threadIdx.x;
    const int tx = t & 15, ty = t >> 4;            // 16x16 thread grid
    const int bn = blockIdx.x;                     // b*NH + n
    const int qt = (gridDim.y - 1) - blockIdx.y;   // heavy tiles dispatched first
    const long base = (long)bn * TT * HD;
    const float* Qe = Kp + base;   // effective queries  = k-projection
    const float* Ke = Qp + base;   // effective keys     = q-projection
    const float* Ve = Vp + base;

    // stage Q tile (rows qt*64 .. qt*64+63)
    #pragma unroll
    for (int it = 0; it < 4; ++it) {
        const int idx = t + it * 256;
        const int r = idx >> 4, d0 = (idx & 15) << 2;
        *(float4*)&Qs[swz_off(r, d0)] =
            *(const float4*)&Qe[(long)(qt * 64 + r) * HD + d0];
    }

    float m[4], l[4], acc[4][4];
    #pragma unroll
    for (int i = 0; i < 4; ++i) {
        m[i] = -__builtin_inff(); l[i] = 0.f;
        #pragma unroll
        for (int j = 0; j < 4; ++j) acc[i][j] = 0.f;
    }

    for (int kt = 0; kt <= qt; ++kt) {
        // prefetch K/V tile into registers before the barrier
        float4 kreg[4], vreg[4];
        #pragma unroll
        for (int it = 0; it < 4; ++it) {
            const int idx = t + it * 256;
            const int r = idx >> 4, d0 = (idx & 15) << 2;
            kreg[it] = *(const float4*)&Ke[(long)(kt * 64 + r) * HD + d0];
            vreg[it] = *(const float4*)&Ve[(long)(kt * 64 + r) * HD + d0];
        }
        __syncthreads();   // prior iteration done reading Ks/Vs (and Qs staged, 1st iter)
        #pragma unroll
        for (int it = 0; it < 4; ++it) {
            const int idx = t + it * 256;
            const int r = idx >> 4, d0 = (idx & 15) << 2;
            *(float4*)&Ks[swz_off(r, d0)] = kreg[it];
            *(float4*)&Vs[swz_off(r, d0)] = vreg[it];
        }
        __syncthreads();

        // ---- scores: s[rr][cc] = Qeff[ty*4+rr] . Keff[tx*4+cc]
        float s[4][4] = {};
        #pragma unroll
        for (int d0 = 0; d0 < HD; d0 += 4) {
            float4 q4[4], k4[4];
            #pragma unroll
            for (int rr = 0; rr < 4; ++rr) q4[rr] = *(const float4*)&Qs[swz_off((ty << 2) + rr, d0)];
            #pragma unroll
            for (int cc = 0; cc < 4; ++cc) k4[cc] = *(const float4*)&Ks[swz_off((tx << 2) + cc, d0)];
            #pragma unroll
            for (int rr = 0; rr < 4; ++rr)
                #pragma unroll
                for (int cc = 0; cc < 4; ++cc)
                    s[rr][cc] += q4[rr].x * k4[cc].x + q4[rr].y * k4[cc].y +
                                 q4[rr].z * k4[cc].z + q4[rr].w * k4[cc].w;
        }
        // scale + causal mask (only the diagonal tile is partial)
        #pragma unroll
        for (int rr = 0; rr < 4; ++rr)
            #pragma unroll
            for (int cc = 0; cc < 4; ++cc)
                s[rr][cc] *= 0.125f;
        if (kt == qt) {
            #pragma unroll
            for (int rr = 0; rr < 4; ++rr)
                #pragma unroll
                for (int cc = 0; cc < 4; ++cc)
                    if (((tx << 2) + cc) > ((ty << 2) + rr)) s[rr][cc] = -__builtin_inff();
        }

        // ---- online softmax (row group = 16 consecutive lanes)
        #pragma unroll
        for (int rr = 0; rr < 4; ++rr) {
            float mloc = fmaxf(fmaxf(s[rr][0], s[rr][1]), fmaxf(s[rr][2], s[rr][3]));
            #pragma unroll
            for (int off = 8; off; off >>= 1) mloc = fmaxf(mloc, __shfl_xor(mloc, off, 16));
            const float mnew  = fmaxf(m[rr], mloc);
            const float alpha = __expf(m[rr] - mnew);
            float p0 = __expf(s[rr][0] - mnew), p1 = __expf(s[rr][1] - mnew);
            float p2 = __expf(s[rr][2] - mnew), p3 = __expf(s[rr][3] - mnew);
            float psum = p0 + p1 + p2 + p3;
            #pragma unroll
            for (int off = 8; off; off >>= 1) psum += __shfl_xor(psum, off, 16);
            l[rr] = l[rr] * alpha + psum;
            m[rr] = mnew;
            #pragma unroll
            for (int cc = 0; cc < 4; ++cc) acc[rr][cc] *= alpha;
            float4 p4 = make_float4(p0, p1, p2, p3);
            *(float4*)&Ps[swz_off((ty << 2) + rr, tx << 2)] = p4;
        }
        __syncthreads();

        // ---- PV: acc[rr][cc] += sum_j P[row][j] * V[j][d]
        #pragma unroll
        for (int j0 = 0; j0 < 64; j0 += 4) {
            float4 p4[4], v4[4];
            #pragma unroll
            for (int rr = 0; rr < 4; ++rr) p4[rr] = *(const float4*)&Ps[swz_off((ty << 2) + rr, j0)];
            #pragma unroll
            for (int jj = 0; jj < 4; ++jj) v4[jj] = *(const float4*)&Vs[swz_off(j0 + jj, tx << 2)];
            #pragma unroll
            for (int rr = 0; rr < 4; ++rr) {
                const float pa[4] = {p4[rr].x, p4[rr].y, p4[rr].z, p4[rr].w};
                #pragma unroll
                for (int jj = 0; jj < 4; ++jj) {
                    acc[rr][0] += pa[jj] * v4[jj].x;
                    acc[rr][1] += pa[jj] * v4[jj].y;
                    acc[rr][2] += pa[jj] * v4[jj].z;
                    acc[rr][3] += pa[jj] * v4[jj].w;
                }
            }
        }
    }

    // ---- epilogue: out[b, t=i, n*64+d] = acc / l
    const int b = bn >> 4, n = bn & 15;
    #pragma unroll
    for (int rr = 0; rr < 4; ++rr) {
        const int i = qt * 64 + (ty << 2) + rr;
        const float inv = 1.0f / l[rr];
        float4 o = make_float4(acc[rr][0] * inv, acc[rr][1] * inv,
                               acc[rr][2] * inv, acc[rr][3] * inv);
        *(float4*)&Yb[((long)(b * TT + i)) * CCH + n * HD + (tx << 2)] = o;
    }
}

// ---------------------------------------------------------------------------
extern "C" void kernel_launch(void* const* d_in, const int* in_sizes, int n_in,
                              void* d_out, int out_size, void* d_ws, size_t ws_size,
                              hipStream_t stream) {
    const float* x  = (const float*)d_in[0];
    const float* Wq = (const float*)d_in[1];
    const float* bq = (const float*)d_in[2];
    const float* Wk = (const float*)d_in[3];
    const float* bk = (const float*)d_in[4];
    const float* Wv = (const float*)d_in[5];
    const float* bv = (const float*)d_in[6];
    const float* Wp = (const float*)d_in[7];
    const float* bp = (const float*)d_in[8];
    // d_in[9] = causal mask — deterministic tril, hardcoded in attn_fused.
    float* out = (float*)d_out;

    float* ws = (float*)d_ws;                 // needs 4 * 16 MiB
    float* Qp = ws;                           // [B,NH,T,HD] fp32
    float* Kp = ws + (size_t)4 * 1024 * 1024;
    float* Vp = ws + (size_t)8 * 1024 * 1024;
    float* ab = ws + (size_t)12 * 1024 * 1024; // attention out, [B,T,C]

    const dim3 blk(256);
    const dim3 gg(64, 16);   // (4096/64, 1024/64)
    proj_gemm<true><<<gg, blk, 0, stream>>>(x, Wq, bq, Qp);
    proj_gemm<true><<<gg, blk, 0, stream>>>(x, Wk, bk, Kp);
    proj_gemm<true><<<gg, blk, 0, stream>>>(x, Wv, bv, Vp);
    attn_fused<<<dim3(BB * NH, TT / 64), blk, 0, stream>>>(Qp, Kp, Vp, ab);
    proj_gemm<false><<<gg, blk, 0, stream>>>(ab, Wp, bp, out);
}

// Round 3
// 300.122 us; speedup vs baseline: 4.6223x; 4.6223x over previous
//
#include <hip/hip_runtime.h>
#include <hip/hip_bf16.h>

#define TT 2048
#define NHD 16

typedef __attribute__((ext_vector_type(8))) short bf16x8;
typedef __attribute__((ext_vector_type(4))) float f32x4;
typedef __attribute__((ext_vector_type(8))) unsigned short us8;
typedef __attribute__((ext_vector_type(4))) unsigned short us4;

typedef __attribute__((address_space(1))) void gvoid;
typedef __attribute__((address_space(3))) void svoid;

__device__ __forceinline__ void gll16(const void* g, void* l) {
    __builtin_amdgcn_global_load_lds((gvoid*)g, (svoid*)l, 16, 0, 0);
}

__device__ __forceinline__ unsigned short f2bf(float f) {
    union { float f; unsigned u; } v; v.f = f;
    unsigned r = v.u + 0x7fffu + ((v.u >> 16) & 1u);
    return (unsigned short)(r >> 16);
}
__device__ __forceinline__ float bf2f(unsigned short u) {
    union { unsigned u; float f; } v; v.u = ((unsigned)u) << 16;
    return v.f;
}

#define MFMA16(a, b, c) __builtin_amdgcn_mfma_f32_16x16x32_bf16((a), (b), (c), 0, 0, 0)

// ---------------------------------------------------------------------------
// x fp32 -> hi/lo bf16 (row-major, same layout). 4096*1024 elements, 8/thread.
__global__ __launch_bounds__(256) void convert_x(const float* __restrict__ x,
                                                 unsigned short* __restrict__ xh,
                                                 unsigned short* __restrict__ xl) {
    const int i = blockIdx.x * 256 + threadIdx.x;     // 524288 tasks
    const float4 a = ((const float4*)x)[2 * i];
    const float4 b = ((const float4*)x)[2 * i + 1];
    const float v[8] = {a.x, a.y, a.z, a.w, b.x, b.y, b.z, b.w};
    us8 H, L;
    #pragma unroll
    for (int j = 0; j < 8; ++j) {
        const unsigned short h = f2bf(v[j]);
        H[j] = h;
        L[j] = f2bf(v[j] - bf2f(h));
    }
    ((us8*)xh)[i] = H;
    ((us8*)xl)[i] = L;
}

// ---------------------------------------------------------------------------
// One weight [1024][1024] fp32 -> hi/lo bf16 [n][k] (transposed).
// Launched once per weight into a shared 4 MiB slot (keeps ws <= 60 MiB).
__global__ __launch_bounds__(256) void convert_w(const float* __restrict__ W,
                                                 unsigned short* __restrict__ Wh,
                                                 unsigned short* __restrict__ Wl) {
    __shared__ float tile[32 * 33];
    const int t = threadIdx.x;
    const int k0 = blockIdx.x * 32, n0 = blockIdx.y * 32;

    const int kl_ = t >> 3, nc = (t & 7) * 4;
    const float4 v = *(const float4*)&W[(size_t)(k0 + kl_) * 1024 + n0 + nc];
    tile[(nc + 0) * 33 + kl_] = v.x;
    tile[(nc + 1) * 33 + kl_] = v.y;
    tile[(nc + 2) * 33 + kl_] = v.z;
    tile[(nc + 3) * 33 + kl_] = v.w;
    __syncthreads();
    const int nl = t >> 3, kc = (t & 7) * 4;
    us4 H, L;
    #pragma unroll
    for (int j = 0; j < 4; ++j) {
        const float f = tile[nl * 33 + kc + j];
        const unsigned short h = f2bf(f);
        H[j] = h;
        L[j] = f2bf(f - bf2f(h));
    }
    *(us4*)&Wh[(size_t)(n0 + nl) * 1024 + k0 + kc] = H;
    *(us4*)&Wl[(size_t)(n0 + nl) * 1024 + k0 + kc] = L;
}

// ---------------------------------------------------------------------------
// Split-bf16 GEMM: O = A @ Bt^T + bias. A: hi/lo [4096][1024], Bt: hi/lo [n][k].
// Tile 128x64, BK=64, 256 threads = 4 waves (each 64x32), 3 MFMA per product
// (hi*hi + hi*lo + lo*hi; lo*lo ~ 2^-18, dropped).
// OUTMODE 0: bf16 hi+lo out; 1: hi only; 2: fp32 out.
template <int OUTMODE>
__global__ __launch_bounds__(256, 3)
void proj_gemm(const unsigned short* __restrict__ Ah, const unsigned short* __restrict__ Al,
               const unsigned short* __restrict__ Bh, const unsigned short* __restrict__ Bl,
               const float* __restrict__ bias,
               unsigned short* __restrict__ Oh, unsigned short* __restrict__ Ol,
               float* __restrict__ Of) {
    __shared__ __align__(16) unsigned short sm[24576];   // 48 KB
    unsigned short* sAh = sm;            // [128][64]
    unsigned short* sAl = sm + 8192;
    unsigned short* sBh = sm + 16384;    // [64][64]
    unsigned short* sBl = sm + 20480;

    const int t = threadIdx.x;
    const int lane = t & 63, w = t >> 6;
    const int wr = w >> 1, wc = w & 1;           // wave tile: rows 64*wr, cols 32*wc
    const int l15 = lane & 15, lq = lane >> 4;
    const int row0 = blockIdx.x * 128;
    const int col0 = blockIdx.y * 64;

    f32x4 acc[4][2] = {};

    for (int k0 = 0; k0 < 1024; k0 += 64) {
        __syncthreads();
        #pragma unroll
        for (int cc = 0; cc < 4; ++cc) {         // A: 16 chunks of 8 rows
            const int c = w * 4 + cc;
            const int r = 8 * c + (lane >> 3);
            const int src = (row0 + r) * 1024 + k0 + 8 * ((lane & 7) ^ (r & 7));
            gll16(&Ah[src], &sAh[c * 512]);
            gll16(&Al[src], &sAl[c * 512]);
        }
        #pragma unroll
        for (int cc = 0; cc < 2; ++cc) {         // B: 8 chunks
            const int c = w * 2 + cc;
            const int r = 8 * c + (lane >> 3);
            const int src = (col0 + r) * 1024 + k0 + 8 * ((lane & 7) ^ (r & 7));
            gll16(&Bh[src], &sBh[c * 512]);
            gll16(&Bl[src], &sBl[c * 512]);
        }
        __syncthreads();
        #pragma unroll
        for (int kh = 0; kh < 2; ++kh) {
            bf16x8 aH[4], aL[4], bH[2], bL[2];
            #pragma unroll
            for (int nt = 0; nt < 2; ++nt) {
                const int rn = 32 * wc + 16 * nt + l15;
                const int off = rn * 64 + 8 * ((lq + 4 * kh) ^ (rn & 7));
                bH[nt] = *(const bf16x8*)&sBh[off];
                bL[nt] = *(const bf16x8*)&sBl[off];
            }
            #pragma unroll
            for (int mt = 0; mt < 4; ++mt) {
                const int rm = 64 * wr + 16 * mt + l15;
                const int off = rm * 64 + 8 * ((lq + 4 * kh) ^ (rm & 7));
                aH[mt] = *(const bf16x8*)&sAh[off];
                aL[mt] = *(const bf16x8*)&sAl[off];
            }
            #pragma unroll
            for (int mt = 0; mt < 4; ++mt)
                #pragma unroll
                for (int nt = 0; nt < 2; ++nt) {
                    acc[mt][nt] = MFMA16(aH[mt], bH[nt], acc[mt][nt]);
                    acc[mt][nt] = MFMA16(aH[mt], bL[nt], acc[mt][nt]);
                    acc[mt][nt] = MFMA16(aL[mt], bH[nt], acc[mt][nt]);
                }
        }
    }

    // epilogue: bounce through LDS so global stores are 16B row-major
    __syncthreads();
    float* sc = (float*)sm + w * (64 * 36);      // per-wave 64x36 fp32
    #pragma unroll
    for (int mt = 0; mt < 4; ++mt)
        #pragma unroll
        for (int nt = 0; nt < 2; ++nt) {
            const float bsv = bias[col0 + 32 * wc + 16 * nt + l15];
            #pragma unroll
            for (int r = 0; r < 4; ++r)
                sc[(16 * mt + 4 * lq + r) * 36 + 16 * nt + l15] = acc[mt][nt][r] + bsv;
        }
    asm volatile("" ::: "memory");
    #pragma unroll
    for (int rr = 0; rr < 4; ++rr) {
        const int rl = 16 * rr + (lane >> 2);
        const int c8 = (lane & 3) * 8;
        const float4 f0 = *(const float4*)&sc[rl * 36 + c8];
        const float4 f1 = *(const float4*)&sc[rl * 36 + c8 + 4];
        const float v[8] = {f0.x, f0.y, f0.z, f0.w, f1.x, f1.y, f1.z, f1.w};
        const int gr = row0 + 64 * wr + rl;
        const int gc = col0 + 32 * wc + c8;
        if (OUTMODE == 2) {
            *(float4*)&Of[(size_t)gr * 1024 + gc] = f0;
            *(float4*)&Of[(size_t)gr * 1024 + gc + 4] = f1;
        } else {
            us8 H, L;
            #pragma unroll
            for (int j = 0; j < 8; ++j) {
                const unsigned short h = f2bf(v[j]);
                H[j] = h;
                L[j] = f2bf(v[j] - bf2f(h));
            }
            *(us8*)&Oh[(size_t)gr * 1024 + gc] = H;
            if (OUTMODE == 0) *(us8*)&Ol[(size_t)gr * 1024 + gc] = L;
        }
    }
}

// ---------------------------------------------------------------------------
// Flash attention, swapped roles (row side = k-projection), split-bf16 QK^T,
// plain-bf16 P and V. 256 threads = 4 waves; wave w owns q-rows 16w..16w+15.
__global__ __launch_bounds__(256, 3)
void attn_mfma(const unsigned short* __restrict__ Qh_, const unsigned short* __restrict__ Ql_,
               const unsigned short* __restrict__ Kh_, const unsigned short* __restrict__ Kl_,
               const unsigned short* __restrict__ Vh_,
               unsigned short* __restrict__ Oh, unsigned short* __restrict__ Ol) {
    __shared__ __align__(16) unsigned short sm[24576];   // 48 KB
    unsigned short* sQh = sm;            // [64][64]
    unsigned short* sQl = sm + 4096;
    unsigned short* sKh = sm + 8192;
    unsigned short* sKl = sm + 12288;
    unsigned short* sVt = sm + 16384;    // [d][j] transposed
    unsigned short* sP  = sm + 20480;    // 4 waves x [16][64]

    const int t = threadIdx.x;
    const int lane = t & 63, w = t >> 6;
    const int l15 = lane & 15, lq = lane >> 4;
    const int bn = blockIdx.x;
    const int b = bn >> 4, n = bn & 15;
    const int qt = (gridDim.y - 1) - blockIdx.y;         // heavy tiles first
    const int rowQ0 = b * TT + qt * 64;
    const int colh = n * 64;

    // stage Q tile once (row side)
    #pragma unroll
    for (int cc = 0; cc < 2; ++cc) {
        const int c = w * 2 + cc;
        const int r = 8 * c + (lane >> 3);
        const int src = (rowQ0 + r) * 1024 + colh + 8 * ((lane & 7) ^ (r & 7));
        gll16(&Qh_[src], &sQh[c * 512]);
        gll16(&Ql_[src], &sQl[c * 512]);
    }

    float m_[4], l_[4];
    f32x4 o[4] = {};
    #pragma unroll
    for (int r = 0; r < 4; ++r) { m_[r] = -1e30f; l_[r] = 0.f; }

    for (int kt = 0; kt <= qt; ++kt) {
        const int rowK0 = b * TT + kt * 64;
        __syncthreads();                                  // prev iter done with sK/sVt
        #pragma unroll
        for (int cc = 0; cc < 2; ++cc) {                  // stage K hi/lo
            const int c = w * 2 + cc;
            const int r = 8 * c + (lane >> 3);
            const int src = (rowK0 + r) * 1024 + colh + 8 * ((lane & 7) ^ (r & 7));
            gll16(&Kh_[src], &sKh[c * 512]);
            gll16(&Kl_[src], &sKl[c * 512]);
        }
        {   // stage V transposed: thread owns column d = lane, j-block 16w..
            const int d = lane;
            unsigned pk[8];
            #pragma unroll
            for (int ip = 0; ip < 8; ++ip) {
                const int j0 = 16 * w + 2 * ip;
                const unsigned short v0 = Vh_[(rowK0 + j0) * 1024 + colh + d];
                const unsigned short v1 = Vh_[(rowK0 + j0 + 1) * 1024 + colh + d];
                pk[ip] = (unsigned)v0 | ((unsigned)v1 << 16);
            }
            unsigned* VtI = (unsigned*)sVt;
            #pragma unroll
            for (int ip = 0; ip < 8; ++ip) {
                const int slot = 2 * w + (ip >> 2);
                VtI[d * 32 + 4 * (slot ^ (d & 7)) + (ip & 3)] = pk[ip];
            }
        }
        __syncthreads();

        // ---- QK^T (split: 3 MFMA per 16x16x32)
        f32x4 s[4] = {};
        const int njt = (kt == qt) ? (w + 1) : 4;         // skip fully-masked tiles
        #pragma unroll
        for (int kh = 0; kh < 2; ++kh) {
            const int rq = 16 * w + l15;
            const int offq = rq * 64 + 8 * ((lq + 4 * kh) ^ (rq & 7));
            const bf16x8 qH = *(const bf16x8*)&sQh[offq];
            const bf16x8 qL = *(const bf16x8*)&sQl[offq];
            #pragma unroll
            for (int jt = 0; jt < 4; ++jt) {
                if (jt >= njt) continue;                  // wave-uniform branch
                const int rk = 16 * jt + l15;
                const int offk = rk * 64 + 8 * ((lq + 4 * kh) ^ (rk & 7));
                const bf16x8 kH = *(const bf16x8*)&sKh[offk];
                const bf16x8 kL = *(const bf16x8*)&sKl[offk];
                s[jt] = MFMA16(qH, kH, s[jt]);
                s[jt] = MFMA16(qH, kL, s[jt]);
                s[jt] = MFMA16(qL, kH, s[jt]);
            }
        }
        if (kt == qt) {                                    // causal mask on diagonal
            #pragma unroll
            for (int jt = 0; jt < 4; ++jt)
                #pragma unroll
                for (int r = 0; r < 4; ++r)
                    if (16 * jt + l15 > 16 * w + 4 * lq + r) s[jt][r] = -1e30f;
        }

        // ---- online softmax (rows shared by 16 consecutive lanes)
        float po[4][4];
        #pragma unroll
        for (int r = 0; r < 4; ++r) {
            float mx = fmaxf(fmaxf(s[0][r], s[1][r]), fmaxf(s[2][r], s[3][r]));
            #pragma unroll
            for (int off = 8; off; off >>= 1) mx = fmaxf(mx, __shfl_xor(mx, off, 16));
            const float mnew = fmaxf(m_[r], mx);
            const float alpha = __expf((m_[r] - mnew) * 0.125f);
            m_[r] = mnew;
            float ps = 0.f;
            #pragma unroll
            for (int jt = 0; jt < 4; ++jt) {
                const float p = __expf((s[jt][r] - mnew) * 0.125f);
                po[r][jt] = p;
                ps += p;
            }
            #pragma unroll
            for (int off = 8; off; off >>= 1) ps += __shfl_xor(ps, off, 16);
            l_[r] = l_[r] * alpha + ps;
            #pragma unroll
            for (int dt = 0; dt < 4; ++dt) o[dt][r] *= alpha;
        }
        // write P (bf16) to per-wave LDS region
        unsigned short* Pw = sP + w * 1024;
        #pragma unroll
        for (int r = 0; r < 4; ++r) {
            const int rl = 4 * lq + r;
            #pragma unroll
            for (int jt = 0; jt < 4; ++jt) {
                const int c = 16 * jt + l15;
                Pw[rl * 64 + 8 * ((c >> 3) ^ (rl & 7)) + (c & 7)] = f2bf(po[r][jt]);
            }
        }
        __syncthreads();

        // ---- PV (plain bf16)
        #pragma unroll
        for (int kh = 0; kh < 2; ++kh) {
            const int offp = l15 * 64 + 8 * ((lq + 4 * kh) ^ (l15 & 7));
            const bf16x8 pa = *(const bf16x8*)&Pw[offp];
            #pragma unroll
            for (int dt = 0; dt < 4; ++dt) {
                const int rd = 16 * dt + l15;
                const int offv = rd * 64 + 8 * ((lq + 4 * kh) ^ (rd & 7));
                const bf16x8 vb = *(const bf16x8*)&sVt[offv];
                o[dt] = MFMA16(pa, vb, o[dt]);
            }
        }
    }

    // ---- epilogue: normalize, bounce through LDS, store hi/lo bf16
    float inv[4];
    #pragma unroll
    for (int r = 0; r < 4; ++r) inv[r] = 1.0f / l_[r];
    float* sc = (float*)sm + w * (16 * 68);
    #pragma unroll
    for (int dt = 0; dt < 4; ++dt)
        #pragma unroll
        for (int r = 0; r < 4; ++r)
            sc[(4 * lq + r) * 68 + 16 * dt + l15] = o[dt][r] * inv[r];
    asm volatile("" ::: "memory");
    #pragma unroll
    for (int it = 0; it < 2; ++it) {
        const int rl = 8 * it + (lane >> 3);
        const int c8 = (lane & 7) * 8;
        const float4 f0 = *(const float4*)&sc[rl * 68 + c8];
        const float4 f1 = *(const float4*)&sc[rl * 68 + c8 + 4];
        const float v[8] = {f0.x, f0.y, f0.z, f0.w, f1.x, f1.y, f1.z, f1.w};
        us8 H, L;
        #pragma unroll
        for (int j = 0; j < 8; ++j) {
            const unsigned short h = f2bf(v[j]);
            H[j] = h;
            L[j] = f2bf(v[j] - bf2f(h));
        }
        const int gt = rowQ0 + 16 * w + rl;
        *(us8*)&Oh[(size_t)gt * 1024 + colh + c8] = H;
        *(us8*)&Ol[(size_t)gt * 1024 + colh + c8] = L;
    }
}

// ---------------------------------------------------------------------------
extern "C" void kernel_launch(void* const* d_in, const int* in_sizes, int n_in,
                              void* d_out, int out_size, void* d_ws, size_t ws_size,
                              hipStream_t stream) {
    const float* x  = (const float*)d_in[0];
    const float* Wq = (const float*)d_in[1];
    const float* bq = (const float*)d_in[2];
    const float* Wk = (const float*)d_in[3];
    const float* bk = (const float*)d_in[4];
    const float* Wv = (const float*)d_in[5];
    const float* bv = (const float*)d_in[6];
    const float* Wp = (const float*)d_in[7];
    const float* bp = (const float*)d_in[8];
    float* out = (float*)d_out;

    char* p = (char*)d_ws;                                // peak 60 MiB
    const size_t MB = 1024 * 1024;
    unsigned short* xh = (unsigned short*)(p);            //  8 MB
    unsigned short* xl = (unsigned short*)(p + 8 * MB);   //  8 MB
    unsigned short* qh = (unsigned short*)(p + 16 * MB);
    unsigned short* ql = (unsigned short*)(p + 24 * MB);
    unsigned short* kh = (unsigned short*)(p + 32 * MB);
    unsigned short* kl = (unsigned short*)(p + 40 * MB);
    unsigned short* vh = (unsigned short*)(p + 48 * MB);
    unsigned short* wh = (unsigned short*)(p + 56 * MB);  // 2 MB, reused per weight
    unsigned short* wl = (unsigned short*)(p + 58 * MB);  // 2 MB
    unsigned short* oh = xh;                              // x dead after projections
    unsigned short* ol = xl;

    const dim3 blk(256);
    const dim3 gw(32, 32);
    const dim3 gp(32, 16);

    convert_x<<<2048, blk, 0, stream>>>(x, xh, xl);

    convert_w<<<gw, blk, 0, stream>>>(Wq, wh, wl);
    proj_gemm<0><<<gp, blk, 0, stream>>>(xh, xl, wh, wl, bq, qh, ql, nullptr);
    convert_w<<<gw, blk, 0, stream>>>(Wk, wh, wl);
    proj_gemm<0><<<gp, blk, 0, stream>>>(xh, xl, wh, wl, bk, kh, kl, nullptr);
    convert_w<<<gw, blk, 0, stream>>>(Wv, wh, wl);
    proj_gemm<1><<<gp, blk, 0, stream>>>(xh, xl, wh, wl, bv, vh, nullptr, nullptr);

    // row side of the (transposed-score) attention = k-projection
    attn_mfma<<<dim3(32, 32), blk, 0, stream>>>(kh, kl, qh, ql, vh, oh, ol);

    convert_w<<<gw, blk, 0, stream>>>(Wp, wh, wl);
    proj_gemm<2><<<gp, blk, 0, stream>>>(oh, ol, wh, wl, bp, nullptr, nullptr, out);
}